// Round 1
// baseline (333.343 us; speedup 1.0000x reference)
//
#include <hip/hip_runtime.h>
#include <cstdint>

typedef __bf16 bf16;
typedef __bf16 bf16x8 __attribute__((ext_vector_type(8)));
typedef float  f32x4  __attribute__((ext_vector_type(4)));

// ---------------------------------------------------------------------------
// Stage 1a/1b: small fp32 GEMMs -> bf16 output.  C = A(MxK) @ B(KxN) [+bias]
// 64x64 tile, 256 threads, BK=16, classic LDS tiling. Tiny fraction of total.
// ---------------------------------------------------------------------------
__global__ __launch_bounds__(256) void gemm_small(
    const float* __restrict__ A, const float* __restrict__ Bm,
    const float* __restrict__ bias, bf16* __restrict__ Cout,
    int M, int N, int K)
{
    __shared__ float As[64][20];
    __shared__ float Bs[16][68];
    const int tid = threadIdx.x;
    const int m0 = blockIdx.x * 64, n0 = blockIdx.y * 64;
    const int tx = tid & 15, ty = tid >> 4;
    const int arow = tid >> 2, ak = (tid & 3) << 2;
    const int bk = tid >> 4, bc = (tid & 15) << 2;
    const bool avalid = (m0 + arow) < M;
    float acc[4][4] = {};

    for (int k0 = 0; k0 < K; k0 += 16) {
        float4 av = make_float4(0.f, 0.f, 0.f, 0.f);
        if (avalid) av = *(const float4*)&A[(size_t)(m0 + arow) * K + k0 + ak];
        float4 bv = *(const float4*)&Bm[(size_t)(k0 + bk) * N + n0 + bc];
        __syncthreads();                 // previous iteration's reads done
        *(float4*)&As[arow][ak] = av;
        *(float4*)&Bs[bk][bc] = bv;
        __syncthreads();
#pragma unroll
        for (int k = 0; k < 16; ++k) {
            float a[4], b[4];
#pragma unroll
            for (int i = 0; i < 4; ++i) a[i] = As[ty * 4 + i][k];
#pragma unroll
            for (int j = 0; j < 4; ++j) b[j] = Bs[k][tx * 4 + j];
#pragma unroll
            for (int i = 0; i < 4; ++i)
#pragma unroll
                for (int j = 0; j < 4; ++j) acc[i][j] += a[i] * b[j];
        }
    }
#pragma unroll
    for (int i = 0; i < 4; ++i) {
        int row = m0 + ty * 4 + i;
        if (row >= M) continue;
#pragma unroll
        for (int j = 0; j < 4; ++j) {
            int col = n0 + tx * 4 + j;
            float v = acc[i][j] + (bias ? bias[col] : 0.f);
            Cout[(size_t)row * N + col] = (bf16)v;
        }
    }
}

// ---------------------------------------------------------------------------
// Stage 1c: W2 (640x1024 fp32) -> W2T (1024x640 bf16), LDS 32x32 transpose
// ---------------------------------------------------------------------------
__global__ __launch_bounds__(256) void w2_transpose(
    const float* __restrict__ W2, bf16* __restrict__ W2T)
{
    __shared__ float t[32][33];
    const int tx = threadIdx.x, ty = threadIdx.y;
    const int n0 = blockIdx.x * 32, k0 = blockIdx.y * 32;
#pragma unroll
    for (int i = 0; i < 4; ++i)
        t[ty + i * 8][tx] = W2[(size_t)(k0 + ty + i * 8) * 1024 + n0 + tx];
    __syncthreads();
#pragma unroll
    for (int i = 0; i < 4; ++i)
        W2T[(size_t)(n0 + ty + i * 8) * 640 + k0 + tx] = (bf16)t[tx][ty + i * 8];
}

// ---------------------------------------------------------------------------
// Stage 2: fused joint GEMM.
//   M = 8*256*65 = 133120 rows (m -> bt = m/65, u = m%65; hg row = (bt>>8)*65+u)
//   A[m][k] = relu(hf[bt][k] + hgb[row][k])  (bf16, generated per K-step)
//   out[m][n] = sum_k A*W2T[n][k] + b2[n]
// BM=128 BN=256 BK=64, 512 threads = 8 waves (2x4), 64x64 per wave,
// mfma_f32_16x16x32_bf16. LDS tiles XOR-swizzled in 16B chunks (c ^= row&7).
// B staged with global_load_lds (linear LDS dest, pre-swizzled global source).
// ---------------------------------------------------------------------------
__global__ __launch_bounds__(512, 2) void joint_main(
    const bf16* __restrict__ hf, const bf16* __restrict__ hgb,
    const bf16* __restrict__ W2T, const float* __restrict__ b2,
    float* __restrict__ out)
{
    __shared__ bf16 As[128 * 64];   // 16 KB
    __shared__ bf16 Bs[256 * 64];   // 32 KB
    const int tid = threadIdx.x;
    const int n0 = blockIdx.x * 256;
    const int m0 = blockIdx.y * 128;

    // --- A-generation mapping: thread -> (row r, k-quarter) ---
    const int r  = tid >> 2;               // 0..127
    const int kq = (tid & 3) << 4;         // 0,16,32,48 (bf16 elems)
    const int m  = m0 + r;
    const int bt = m / 65;
    const int uu = m - bt * 65;
    const int bb = bt >> 8;
    const bf16* hfp = hf  + (size_t)bt * 640 + kq;
    const bf16* hgp = hgb + (size_t)(bb * 65 + uu) * 640 + kq;
    const int c0 = (tid & 3) << 1;         // first 16B-chunk index (0,2,4,6)
    bf16* asw0 = &As[r * 64 + (((c0    ) ^ (r & 7)) << 3)];
    bf16* asw1 = &As[r * 64 + (((c0 + 1) ^ (r & 7)) << 3)];

    // --- wave mapping ---
    const int wid = tid >> 6, lane = tid & 63;
    const int wr = wid >> 2, wc = wid & 3;       // 2 x 4 waves
    const int lg = lane >> 4, l15 = lane & 15;

    f32x4 acc[4][4] = {};

    for (int step = 0; step < 10; ++step) {
        const int k0 = step * 64;
        // ---- issue B staging: 32 KB via 4 x global_load_lds(16B) ----
        {
            const char* w2b = (const char*)W2T + (size_t)k0 * 2;
#pragma unroll
            for (int call = 0; call < 4; ++call) {
                int chunk = call * 512 + tid;          // 0..2047
                int brow = chunk >> 3, c = chunk & 7;
                const char* src = w2b + (size_t)(n0 + brow) * 1280
                                      + ((c ^ (brow & 7)) << 4);
                __builtin_amdgcn_global_load_lds(
                    (const __attribute__((address_space(1))) uint32_t*)src,
                    (__attribute__((address_space(3))) uint32_t*)&Bs[chunk << 3],
                    16, 0, 0);
            }
        }
        // ---- generate A tile (16 elems/thread), swizzled ds_write_b128 ----
        {
            bf16x8 F0 = *(const bf16x8*)(hfp + k0);
            bf16x8 F1 = *(const bf16x8*)(hfp + k0 + 8);
            bf16x8 G0 = *(const bf16x8*)(hgp + k0);
            bf16x8 G1 = *(const bf16x8*)(hgp + k0 + 8);
            bf16x8 O0, O1;
#pragma unroll
            for (int i = 0; i < 8; ++i) {
                float s = (float)F0[i] + (float)G0[i];
                O0[i] = (bf16)fmaxf(s, 0.f);
            }
#pragma unroll
            for (int i = 0; i < 8; ++i) {
                float s = (float)F1[i] + (float)G1[i];
                O1[i] = (bf16)fmaxf(s, 0.f);
            }
            *(bf16x8*)asw0 = O0;
            *(bf16x8*)asw1 = O1;
        }
        __syncthreads();    // staging (vmcnt) + A writes (lgkm) complete
        // ---- MFMA phase: 32 MFMA / wave ----
#pragma unroll
        for (int kk = 0; kk < 2; ++kk) {
            const int clog = (kk << 2) + lg;
            bf16x8 afr[4], bfr[4];
#pragma unroll
            for (int mi = 0; mi < 4; ++mi) {
                int row = wr * 64 + mi * 16 + l15;
                afr[mi] = *(const bf16x8*)&As[row * 64 + ((clog ^ (row & 7)) << 3)];
            }
#pragma unroll
            for (int ni = 0; ni < 4; ++ni) {
                int row = wc * 64 + ni * 16 + l15;
                bfr[ni] = *(const bf16x8*)&Bs[row * 64 + ((clog ^ (row & 7)) << 3)];
            }
#pragma unroll
            for (int mi = 0; mi < 4; ++mi)
#pragma unroll
                for (int ni = 0; ni < 4; ++ni)
                    acc[mi][ni] = __builtin_amdgcn_mfma_f32_16x16x32_bf16(
                        afr[mi], bfr[ni], acc[mi][ni], 0, 0, 0);
        }
        __syncthreads();    // reads done before next overwrite
    }

    // ---- epilogue: +b2, fp32 stores ----
    float bv[4];
#pragma unroll
    for (int ni = 0; ni < 4; ++ni) bv[ni] = b2[n0 + wc * 64 + ni * 16 + l15];
#pragma unroll
    for (int mi = 0; mi < 4; ++mi) {
#pragma unroll
        for (int ni = 0; ni < 4; ++ni) {
            int col = n0 + wc * 64 + ni * 16 + l15;
#pragma unroll
            for (int j = 0; j < 4; ++j) {
                int row = m0 + wr * 64 + mi * 16 + lg * 4 + j;
                out[(size_t)row * 1024 + col] = acc[mi][ni][j] + bv[ni];
            }
        }
    }
}

// ---------------------------------------------------------------------------
extern "C" void kernel_launch(void* const* d_in, const int* in_sizes, int n_in,
                              void* d_out, int out_size, void* d_ws, size_t ws_size,
                              hipStream_t stream)
{
    const float* f  = (const float*)d_in[0];   // (8,256,1024)
    const float* g  = (const float*)d_in[1];   // (8,65,320)
    const float* W1 = (const float*)d_in[2];   // (1344,640)
    const float* b1 = (const float*)d_in[3];   // (640)
    const float* W2 = (const float*)d_in[4];   // (640,1024)
    const float* b2 = (const float*)d_in[5];   // (1024)
    float* out = (float*)d_out;                // (8,256,65,1024)

    bf16* hf  = (bf16*)d_ws;                   // 2048*640
    bf16* hgb = hf + 2048 * 640;               // 520*640 (g@W1g + b1)
    bf16* W2T = hgb + 520 * 640;               // 1024*640

    // hf = f @ W1[:1024]
    gemm_small<<<dim3(32, 10), 256, 0, stream>>>(f, W1, nullptr, hf, 2048, 640, 1024);
    // hgb = g @ W1[1024:] + b1
    gemm_small<<<dim3(9, 10), 256, 0, stream>>>(g, W1 + 1024 * 640, b1, hgb, 520, 640, 320);
    // W2T = bf16(W2^T)
    w2_transpose<<<dim3(32, 20), dim3(32, 8), 0, stream>>>(W2, W2T);
    // fused joint GEMM
    joint_main<<<dim3(4, 1040), 512, 0, stream>>>(hf, hgb, W2T, b2, out);
}